// Round 16
// baseline (182.397 us; speedup 1.0000x reference)
//
#include <hip/hip_runtime.h>

#define NB 2
#define NH 8
#define NS 2048
#define ND 64
#define QBLK 64
#define KBLK 64
#define NKH 1024            // keys per k-half
#define NTB (NKH / KBLK)    // 16 tiles per pass-B block
#define NTS 4               // stats tiles per wave (512 keys / (32*4))
#define WKT 32              // stats: keys per wave-tile
#define QST 68
#define KSTs 76             // stats K stride
#define KST 76
#define VST 70
#define PST 68

typedef _Float16 f16x4 __attribute__((ext_vector_type(4)));
typedef _Float16 f16x8 __attribute__((ext_vector_type(8)));
typedef float    f32x4 __attribute__((ext_vector_type(4)));

#define MFMA16(A,B,C) __builtin_amdgcn_mfma_f32_16x16x32_f16((A),(B),(C),0,0,0)

static __device__ __forceinline__ f16x8 cat8(f16x4 a, f16x4 b) {
    return __builtin_shufflevector(a, b, 0, 1, 2, 3, 4, 5, 6, 7);
}
static __device__ __forceinline__ f16x8 lds8(const _Float16* p) {
    f16x4 a = *(const f16x4*)p;
    f16x4 b = *(const f16x4*)(p + 4);
    return cat8(a, b);
}
static __device__ __forceinline__ void bar_w() {
    asm volatile("s_waitcnt lgkmcnt(0)" ::: "memory");
    __builtin_amdgcn_sched_barrier(0);
    __builtin_amdgcn_s_barrier();
    __builtin_amdgcn_sched_barrier(0);
}
static __device__ __forceinline__ void dsfence() {
    asm volatile("s_waitcnt lgkmcnt(0)");
    __builtin_amdgcn_sched_barrier(0x7F);
}

// ========== kernel 1: denominators at 4x key-parallelism (round-14 proven) ====
// Partial sums are written TWICE into the attn region: cols [ks] and [1024+ks]
// of each q-row. Each pass-B block reads the copy inside its own k-range
// before overwriting it -> no workspace, no cross-block race.
__global__ __launch_bounds__(256, 4)
void sdpa_stats(const float* __restrict__ Qg, const float* __restrict__ Kg,
                float* __restrict__ Ag)
{
    const int tid  = threadIdx.x;
    const int w    = tid >> 6;
    const int lane = tid & 63;
    const int lg   = lane >> 4;
    const int lc   = lane & 15;

    const int bid = blockIdx.x;
    const int xcd = bid & 7;
    const int r   = bid >> 3;            // 0..255
    const int bh  = 2 * xcd + (r >> 7);  // XCD-pinned
    const int qt_ = (r >> 2) & 31;
    const int ks  = r & 3;               // key-slice (512 keys)

    const size_t base = (size_t)bh * NS * ND;
    const float* Qp = Qg + base + (size_t)qt_ * QBLK * ND;
    const float* Kp = Kg + base + (size_t)ks * 512 * ND;

    __shared__ __align__(16) unsigned char pool[20480];
    _Float16* Qs = (_Float16*)pool;                      // prologue only
    _Float16* Ks = (_Float16*)(pool + (size_t)w * 4864);
    float*   MLs = (float*)(pool + 19456);

    {
        const int srow = tid >> 4, sd0 = (tid & 15) * 4;
        #pragma unroll
        for (int it = 0; it < 4; ++it) {
            const int rr = srow + 16 * it;
            float4 f = *(const float4*)&Qp[(size_t)rr * ND + sd0];
            f16x4 h = { (_Float16)(f.x * 0.125f), (_Float16)(f.y * 0.125f),
                        (_Float16)(f.z * 0.125f), (_Float16)(f.w * 0.125f) };
            *(f16x4*)&Qs[rr * QST + sd0] = h;
        }
    }
    __syncthreads();
    f16x8 qfa[4], qfb[4];
    #pragma unroll
    for (int qt = 0; qt < 4; ++qt) {
        qfa[qt] = lds8(&Qs[(16 * qt + lc) * QST + 8 * lg]);
        qfb[qt] = lds8(&Qs[(16 * qt + lc) * QST + 8 * lg + 32]);
    }
    __syncthreads();

    float lacc[4] = {0.f, 0.f, 0.f, 0.f};

    for (int t = 0; t < NTS; ++t) {
        const int koff = (4 * t + w) * WKT;
        {
            float4 kr[8];
            #pragma unroll
            for (int i = 0; i < 8; ++i)
                kr[i] = *(const float4*)&Kp[(size_t)koff * ND + i * 256 + 4 * lane];
            #pragma unroll
            for (int i = 0; i < 8; ++i) {
                f16x4 h = { (_Float16)kr[i].x, (_Float16)kr[i].y,
                            (_Float16)kr[i].z, (_Float16)kr[i].w };
                *(f16x4*)&Ks[(4 * i + lg) * KSTs + 4 * lc] = h;
            }
        }
        dsfence();

        __builtin_amdgcn_s_setprio(1);
        #pragma unroll
        for (int mt = 0; mt < 2; ++mt) {
            f16x8 a0 = lds8(&Ks[(16 * mt + lc) * KSTs + 8 * lg]);
            f16x8 a1 = lds8(&Ks[(16 * mt + lc) * KSTs + 8 * lg + 32]);
            #pragma unroll
            for (int qt = 0; qt < 4; ++qt) {
                f32x4 z = {0.f, 0.f, 0.f, 0.f};
                z = MFMA16(a0, qfa[qt], z);
                z = MFMA16(a1, qfb[qt], z);
                #pragma unroll
                for (int rr = 0; rr < 4; ++rr)
                    lacc[qt] += __expf(z[rr]);
            }
        }
        __builtin_amdgcn_s_setprio(0);
        __builtin_amdgcn_sched_barrier(0x7F);
    }

    #pragma unroll
    for (int qt = 0; qt < 4; ++qt) {
        lacc[qt] += __shfl_xor(lacc[qt], 16);
        lacc[qt] += __shfl_xor(lacc[qt], 32);
    }
    if (lg == 0) {
        #pragma unroll
        for (int qt = 0; qt < 4; ++qt)
            MLs[w * 64 + 16 * qt + lc] = lacc[qt];
    }
    __syncthreads();
    if (tid < 64) {
        const float s = MLs[tid] + MLs[64 + tid] + MLs[128 + tid] + MLs[192 + tid];
        float* Ab = Ag + (size_t)bh * NS * NS + ((size_t)qt_ * QBLK + tid) * NS;
        Ab[ks]        = s;      // copy for kh=0 block
        Ab[1024 + ks] = s;      // copy for kh=1 block
    }
}

// ========== kernel 2: attn write + PV, k-split x2, 16-q-per-wave interior =====
__global__ __launch_bounds__(256, 4)
void sdpa_passb(const float* __restrict__ Qg, const float* __restrict__ Kg,
                const float* __restrict__ Vg, float* __restrict__ Ag,
                float* __restrict__ dst0, float* __restrict__ dst1,
                int khBase, int khMul, int accum)
{
    const int tid  = threadIdx.x;
    const int w    = tid >> 6;
    const int lane = tid & 63;
    const int lg   = lane >> 4;
    const int lc   = lane & 15;

    // XCD-pinned decode; both k-halves of (bh,qt) land on the same XCD.
    const int bid = blockIdx.x;
    const int xcd = bid & 7;
    const int j   = bid >> 3;
    const int kh  = khBase + (khMul ? (j & 1) : 0);
    const int jj  = khMul ? (j >> 1) : j;        // 0..63
    const int bh  = 2 * xcd + (jj >> 5);
    const int qt_ = jj & 31;
    float* Odst   = (khMul && (j & 1)) ? dst1 : dst0;

    const size_t base = (size_t)bh * NS * ND;
    const float* Qp = Qg + base + (size_t)qt_ * QBLK * ND;
    const float* Kp = Kg + base + (size_t)kh * NKH * ND;
    const float* Vp = Vg + base + (size_t)kh * NKH * ND;
    float*       Op = Odst + base + (size_t)qt_ * QBLK * ND;
    float*       Ap = Ag + (size_t)bh * NS * NS + (size_t)qt_ * QBLK * NS;

    // LDS: Ks 9728 | VT 8960 | union(Qs, Ps) 8704 = 27392 B -> 4 blocks/CU
    __shared__ __align__(16) unsigned char pool[27392];
    _Float16* Ks = (_Float16*)pool;
    _Float16* VT = (_Float16*)(pool + 9728);
    _Float16* Qs = (_Float16*)(pool + 18688);
    _Float16* Ps = (_Float16*)(pool + 18688);

    const int srow = tid >> 4;          // 0..15
    const int sd0  = (tid & 15) * 4;    // 0..60
    const int vq   = tid >> 4;          // V: key quad 4*vq
    const int vd   = tid & 15;          // V: d quad 4*vd

    // ---- stage Q (scaled by 1/T = 1/8, exact) ----
    #pragma unroll
    for (int it = 0; it < 4; ++it) {
        const int rr = srow + 16 * it;
        float4 f = *(const float4*)&Qp[(size_t)rr * ND + sd0];
        f16x4 h = { (_Float16)(f.x * 0.125f), (_Float16)(f.y * 0.125f),
                    (_Float16)(f.z * 0.125f), (_Float16)(f.w * 0.125f) };
        *(f16x4*)&Qs[rr * QST + sd0] = h;
    }
    __syncthreads();
    const int q = 16 * w + lc;          // this lane's query row
    const f16x8 qf0 = lds8(&Qs[q * QST + 8 * lg]);
    const f16x8 qf1 = lds8(&Qs[q * QST + 8 * lg + 32]);
    __syncthreads();                    // Qs dead; Ps overlays it

    // merged denominator from stats (copy inside OUR k-range; overwritten at t=0)
    float il;
    {
        const float4 sv = *(const float4*)&Ap[(size_t)q * NS + kh * NKH];
        il = 1.0f / (sv.x + sv.y + sv.z + sv.w);
    }

    float4 kr[4], vr[4];
    auto loadK = [&](int t) {
        #pragma unroll
        for (int it = 0; it < 4; ++it)
            kr[it] = *(const float4*)&Kp[(size_t)(t * KBLK + srow + 16 * it) * ND + sd0];
    };
    auto writeK = [&]() {
        #pragma unroll
        for (int it = 0; it < 4; ++it) {
            f16x4 h = { (_Float16)kr[it].x, (_Float16)kr[it].y,
                        (_Float16)kr[it].z, (_Float16)kr[it].w };
            *(f16x4*)&Ks[(srow + 16 * it) * KST + sd0] = h;
        }
    };
    auto loadV = [&](int t) {
        #pragma unroll
        for (int rr = 0; rr < 4; ++rr)
            vr[rr] = *(const float4*)&Vp[(size_t)(t * KBLK + 4 * vq + rr) * ND + 4 * vd];
    };
    auto writeVT = [&]() {              // 4x4 in-register transpose -> b64 writes
        #pragma unroll
        for (int jx = 0; jx < 4; ++jx) {
            f16x4 col = { (_Float16)vr[0][jx], (_Float16)vr[1][jx],
                          (_Float16)vr[2][jx], (_Float16)vr[3][jx] };
            *(f16x4*)&VT[(4 * vd + jx) * VST + 4 * vq] = col;
        }
    };

    f32x4 acc[4];                       // O^T partial for this wave's 16 q
    #pragma unroll
    for (int dt = 0; dt < 4; ++dt) acc[dt] = {0.f, 0.f, 0.f, 0.f};

    loadK(0); loadV(0);
    for (int t = 0; t < NTB; ++t) {
        writeK(); writeVT();            // stage t (write-first order: proven)
        { const int n = t + 1 < NTB ? t + 1 : 0; loadK(n); loadV(n); }
        bar_w();                        // staging visible to all waves

        // QK^T: S^T rows = 64 keys (4 mt), cols = this wave's 16 q
        f32x4 s[4];
        __builtin_amdgcn_s_setprio(1);
        #pragma unroll
        for (int mt = 0; mt < 4; ++mt) {
            f16x8 a0 = lds8(&Ks[(16 * mt + lc) * KST + 8 * lg]);
            f16x8 a1 = lds8(&Ks[(16 * mt + lc) * KST + 8 * lg + 32]);
            f32x4 z = {0.f, 0.f, 0.f, 0.f};
            z = MFMA16(a0, qf0, z);
            z = MFMA16(a1, qf1, z);
            s[mt] = z;
        }
        __builtin_amdgcn_s_setprio(0);

        // p = exp(s)*il -> f16 Ps (own q row)
        #pragma unroll
        for (int mt = 0; mt < 4; ++mt) {
            f32x4 p;
            #pragma unroll
            for (int rr = 0; rr < 4; ++rr)
                p[rr] = __expf(s[mt][rr]) * il;
            f16x4 ph = { (_Float16)p[0], (_Float16)p[1],
                         (_Float16)p[2], (_Float16)p[3] };
            *(f16x4*)&Ps[q * PST + 16 * mt + 4 * lg] = ph;
        }
        asm volatile("s_waitcnt lgkmcnt(0)" ::: "memory");  // own P rows ready
        __builtin_amdgcn_sched_barrier(0);

        // PV: O^T += V^T . P^T (2 k-slices of 32)
        f16x8 bf0 = lds8(&Ps[q * PST + 8 * lg]);
        f16x8 bf1 = lds8(&Ps[q * PST + 32 + 8 * lg]);
        __builtin_amdgcn_s_setprio(1);
        #pragma unroll
        for (int dt = 0; dt < 4; ++dt) {
            f16x8 af0 = lds8(&VT[(16 * dt + lc) * VST + 8 * lg]);
            f16x8 af1 = lds8(&VT[(16 * dt + lc) * VST + 32 + 8 * lg]);
            acc[dt] = MFMA16(af0, bf0, acc[dt]);
            acc[dt] = MFMA16(af1, bf1, acc[dt]);
        }
        __builtin_amdgcn_s_setprio(0);

        bar_w();                        // all Ks/VT reads done; all Ps(t) visible

        // attn store: readback full-tile Ps, cvt f16->f32, 128B-contiguous rows
        #pragma unroll
        for (int i = 0; i < 4; ++i) {
            const int qr = 32 * (i & 1) + (tid >> 3);
            const int kc = 32 * (i >> 1) + 4 * (tid & 7);
            f16x4 ph = *(const f16x4*)&Ps[qr * PST + kc];
            f32x4 pf = { (float)ph[0], (float)ph[1], (float)ph[2], (float)ph[3] };
            *(f32x4*)&Ap[(size_t)qr * NS + kh * NKH + t * KBLK + kc] = pf;
        }
        // next bar_w's lgkmcnt(0) drains these Ps reads before Ps(t+1) writes
    }

    // ---- partial O store (each wave owns its 16 q rows exclusively) ----
    #pragma unroll
    for (int dt = 0; dt < 4; ++dt) {
        float* ad = &Op[(size_t)q * ND + 16 * dt + 4 * lg];
        f32x4 v = acc[dt];
        if (accum) v = v + *(const f32x4*)ad;
        *(f32x4*)ad = v;
    }
}

// ========== kernel 3: O merge ==========
__global__ __launch_bounds__(256)
void add_o(float* __restrict__ O, const float* __restrict__ P)
{
    const size_t i = (size_t)blockIdx.x * 256 + threadIdx.x;
    f32x4* O4 = (f32x4*)O;
    const f32x4* P4 = (const f32x4*)P;
    O4[i] = O4[i] + P4[i];
}

extern "C" void kernel_launch(void* const* d_in, const int* in_sizes, int n_in,
                              void* d_out, int out_size, void* d_ws, size_t ws_size,
                              hipStream_t stream) {
    const float* q = (const float*)d_in[0];
    const float* k = (const float*)d_in[1];
    const float* v = (const float*)d_in[2];
    float* out  = (float*)d_out;
    float* attn = out + (size_t)NB * NH * NS * ND;   // outputs: (output, attn)
    float* wsO  = (float*)d_ws;
    const size_t oElems = (size_t)NB * NH * NS * ND; // 2M floats

    sdpa_stats<<<dim3(32 * NB * NH * 4), 256, 0, stream>>>(q, k, attn);

    if (ws_size >= oElems * sizeof(float)) {
        // both k-halves in one dispatch: kh0 -> out, kh1 -> ws; then add
        sdpa_passb<<<dim3(32 * NB * NH * 2), 256, 0, stream>>>(
            q, k, v, attn, out, wsO, 0, 1, 0);
        add_o<<<dim3(oElems / (256 * 4)), 256, 0, stream>>>(out, wsO);
    } else {
        // fallback: serialize the halves, second accumulates into out
        sdpa_passb<<<dim3(32 * NB * NH), 256, 0, stream>>>(
            q, k, v, attn, out, out, 0, 0, 0);
        sdpa_passb<<<dim3(32 * NB * NH), 256, 0, stream>>>(
            q, k, v, attn, out, out, 1, 0, 1);
    }
}

// Round 17
// 125.724 us; speedup vs baseline: 1.4508x; 1.4508x over previous
//
#include <hip/hip_runtime.h>

#define NB 2
#define NH 8
#define NS 2048
#define ND 64
#define NKH 1024            // keys per k-half
#define WKT 32              // keys per wave-tile
#define NTB 8               // passB tiles per wave (1024 / (32*4))
#define NTS 4               // stats tiles per wave (512 / (32*4))
#define QST 68
#define KST 68
#define KSTs 76
#define VST 36
#define PST 36
#define OST 68

typedef _Float16 f16x4 __attribute__((ext_vector_type(4)));
typedef _Float16 f16x8 __attribute__((ext_vector_type(8)));
typedef float    f32x4 __attribute__((ext_vector_type(4)));

#define MFMA16(A,B,C) __builtin_amdgcn_mfma_f32_16x16x32_f16((A),(B),(C),0,0,0)

static __device__ __forceinline__ f16x8 cat8(f16x4 a, f16x4 b) {
    return __builtin_shufflevector(a, b, 0, 1, 2, 3, 4, 5, 6, 7);
}
static __device__ __forceinline__ f16x4 tof16(float4 f) {
    return (f16x4){ (_Float16)f.x, (_Float16)f.y, (_Float16)f.z, (_Float16)f.w };
}
static __device__ __forceinline__ f16x8 lds8(const _Float16* p) {
    f16x4 a = *(const f16x4*)p;          // ds_read_b64 pair
    f16x4 b = *(const f16x4*)(p + 4);
    return cat8(a, b);
}
static __device__ __forceinline__ void dsfence() {
    asm volatile("s_waitcnt lgkmcnt(0)");
    __builtin_amdgcn_sched_barrier(0x7F);
}

// ========== kernel 1: denominators at 4x key-parallelism (r14/r16 proven) =====
// Row-sums per 512-key slice written TWICE into the attn region (cols ks and
// 1024+ks); each passB block reads the copy inside its own half, then
// overwrites it at t=0. No workspace, no race.
__global__ __launch_bounds__(256, 4)
void sdpa_stats(const float* __restrict__ Qg, const float* __restrict__ Kg,
                float* __restrict__ Ag)
{
    const int tid  = threadIdx.x;
    const int w    = tid >> 6;
    const int lane = tid & 63;
    const int lg   = lane >> 4;
    const int lc   = lane & 15;

    const int bid = blockIdx.x;
    const int xcd = bid & 7;
    const int r   = bid >> 3;            // 0..255
    const int bh  = 2 * xcd + (r >> 7);  // XCD-pinned
    const int qt_ = (r >> 2) & 31;
    const int ks  = r & 3;

    const size_t base = (size_t)bh * NS * ND;
    const float* Qp = Qg + base + (size_t)qt_ * 64 * ND;
    const float* Kp = Kg + base + (size_t)ks * 512 * ND;

    __shared__ __align__(16) unsigned char pool[20480];
    _Float16* Qs = (_Float16*)pool;
    _Float16* Ks = (_Float16*)(pool + (size_t)w * 4864);
    float*   MLs = (float*)(pool + 19456);

    {
        const int srow = tid >> 4, sd0 = (tid & 15) * 4;
        #pragma unroll
        for (int it = 0; it < 4; ++it) {
            const int rr = srow + 16 * it;
            float4 f = *(const float4*)&Qp[(size_t)rr * ND + sd0];
            f16x4 h = { (_Float16)(f.x * 0.125f), (_Float16)(f.y * 0.125f),
                        (_Float16)(f.z * 0.125f), (_Float16)(f.w * 0.125f) };
            *(f16x4*)&Qs[rr * QST + sd0] = h;
        }
    }
    __syncthreads();
    f16x8 qfa[4], qfb[4];
    #pragma unroll
    for (int qt = 0; qt < 4; ++qt) {
        qfa[qt] = lds8(&Qs[(16 * qt + lc) * QST + 8 * lg]);
        qfb[qt] = lds8(&Qs[(16 * qt + lc) * QST + 8 * lg + 32]);
    }
    __syncthreads();

    float lacc[4] = {0.f, 0.f, 0.f, 0.f};

    for (int t = 0; t < NTS; ++t) {
        const int koff = (4 * t + w) * WKT;
        {
            float4 kr[8];
            #pragma unroll
            for (int i = 0; i < 8; ++i)
                kr[i] = *(const float4*)&Kp[(size_t)koff * ND + i * 256 + 4 * lane];
            #pragma unroll
            for (int i = 0; i < 8; ++i)
                *(f16x4*)&Ks[(4 * i + lg) * KSTs + 4 * lc] = tof16(kr[i]);
        }
        dsfence();

        __builtin_amdgcn_s_setprio(1);
        #pragma unroll
        for (int mt = 0; mt < 2; ++mt) {
            f16x8 a0 = lds8(&Ks[(16 * mt + lc) * KSTs + 8 * lg]);
            f16x8 a1 = lds8(&Ks[(16 * mt + lc) * KSTs + 8 * lg + 32]);
            #pragma unroll
            for (int qt = 0; qt < 4; ++qt) {
                f32x4 z = {0.f, 0.f, 0.f, 0.f};
                z = MFMA16(a0, qfa[qt], z);
                z = MFMA16(a1, qfb[qt], z);
                #pragma unroll
                for (int rr = 0; rr < 4; ++rr)
                    lacc[qt] += __expf(z[rr]);
            }
        }
        __builtin_amdgcn_s_setprio(0);
        __builtin_amdgcn_sched_barrier(0x7F);
    }

    #pragma unroll
    for (int qt = 0; qt < 4; ++qt) {
        lacc[qt] += __shfl_xor(lacc[qt], 16);
        lacc[qt] += __shfl_xor(lacc[qt], 32);
    }
    if (lg == 0) {
        #pragma unroll
        for (int qt = 0; qt < 4; ++qt)
            MLs[w * 64 + 16 * qt + lc] = lacc[qt];
    }
    __syncthreads();
    if (tid < 64) {
        const float s = MLs[tid] + MLs[64 + tid] + MLs[128 + tid] + MLs[192 + tid];
        float* Ab = Ag + (size_t)bh * NS * NS + ((size_t)qt_ * 64 + tid) * NS;
        Ab[ks]       = s;
        Ab[NKH + ks] = s;
    }
}

// ========== kernel 2: attn + PV, k-split x2, r13 WAVE-PRIVATE interior ========
__global__ __launch_bounds__(256, 3)
void sdpa_passb(const float* __restrict__ Qg, const float* __restrict__ Kg,
                const float* __restrict__ Vg, float* __restrict__ Ag,
                float* __restrict__ dst0, float* __restrict__ dst1,
                int khBase, int khMul, int accum)
{
    const int tid  = threadIdx.x;
    const int w    = tid >> 6;
    const int lane = tid & 63;
    const int lg   = lane >> 4;
    const int lc   = lane & 15;

    // XCD-pinned decode; both k-halves of (bh,qt) on the same XCD.
    const int bid = blockIdx.x;
    const int xcd = bid & 7;
    const int rst = bid >> 3;
    int bh, qt_, kh;
    if (khMul) { bh = 2 * xcd + (rst >> 6); const int in_ = rst & 63;
                 qt_ = in_ >> 1; kh = khBase + (in_ & 1); }
    else       { bh = 2 * xcd + (rst >> 5); qt_ = rst & 31; kh = khBase; }
    float* Odst = (khMul && kh) ? dst1 : dst0;

    const size_t base = (size_t)bh * NS * ND;
    const float* Qp = Qg + base + (size_t)qt_ * 64 * ND;
    const float* Kp = Kg + base + (size_t)kh * NKH * ND;
    const float* Vp = Vg + base + (size_t)kh * NKH * ND;
    float*       Op = Odst + base + (size_t)qt_ * 64 * ND;
    float*       Ap = Ag + (size_t)bh * NS * NS + (size_t)qt_ * 64 * NS;

    // KV[w] 4608 (K rows32xKST68 / VT rows64xVST36 TIME-SHARED) | Ps[w] 4608
    // Qs (prologue) and Obuf (epilogue) overlay the KV region. Total 36864 B.
    __shared__ __align__(16) unsigned char pool[36864];
    _Float16* Qs = (_Float16*)pool;
    _Float16* KV = (_Float16*)(pool + (size_t)w * 4608);
    _Float16* Ps = (_Float16*)(pool + 18432 + (size_t)w * 4608);
    float*  Obuf = (float*)pool;

    {
        const int srow = tid >> 4, sd0 = (tid & 15) * 4;
        #pragma unroll
        for (int it = 0; it < 4; ++it) {
            const int rr = srow + 16 * it;
            float4 f = *(const float4*)&Qp[(size_t)rr * ND + sd0];
            f16x4 h = { (_Float16)(f.x * 0.125f), (_Float16)(f.y * 0.125f),
                        (_Float16)(f.z * 0.125f), (_Float16)(f.w * 0.125f) };
            *(f16x4*)&Qs[rr * QST + sd0] = h;
        }
    }
    __syncthreads();
    f16x8 qfa[4], qfb[4];
    #pragma unroll
    for (int qt = 0; qt < 4; ++qt) {
        qfa[qt] = lds8(&Qs[(16 * qt + lc) * QST + 8 * lg]);
        qfb[qt] = lds8(&Qs[(16 * qt + lc) * QST + 8 * lg + 32]);
    }
    // merged denominators (stats copies live in OUR half's first 4 columns)
    float il[4];
    #pragma unroll
    for (int qt = 0; qt < 4; ++qt) {
        const float4 sv = *(const float4*)&Ap[(size_t)(16 * qt + lc) * NS + kh * NKH];
        il[qt] = 1.0f / (sv.x + sv.y + sv.z + sv.w);
    }
    __syncthreads();   // all il reads done before any wave's t=0 store; Qs dead

    const int vkq = lane >> 3;
    const int vdg = lane & 7;

    f32x4 acc[4][4];
    #pragma unroll
    for (int dt = 0; dt < 4; ++dt)
        #pragma unroll
        for (int qt = 0; qt < 4; ++qt)
            acc[dt][qt] = {0.f, 0.f, 0.f, 0.f};

    float4 kr[8], vr[8];
    #pragma unroll
    for (int i = 0; i < 8; ++i)      // preload K tile 0
        kr[i] = *(const float4*)&Kp[(size_t)(w * WKT) * ND + i * 256 + 4 * lane];

    for (int t = 0; t < NTB; ++t) {
        const int koff = (4 * t + w) * WKT;
        // ---- stage K(t) from regs (vmcnt waits only on K loads: older than stores)
        #pragma unroll
        for (int i = 0; i < 8; ++i)
            *(f16x4*)&KV[(4 * i + lg) * KST + 4 * lc] = tof16(kr[i]);
        // ---- issue V(t) loads (hide under QK^T)
        #pragma unroll
        for (int rr = 0; rr < 4; ++rr)
            #pragma unroll
            for (int h = 0; h < 2; ++h)
                vr[2 * rr + h] = *(const float4*)
                    &Vp[(size_t)(koff + 4 * vkq + rr) * ND + 8 * vdg + 4 * h];
        dsfence();

        // ---- QK^T -> exp -> Ps (per-mt fused, low VGPR)
        __builtin_amdgcn_s_setprio(1);
        #pragma unroll
        for (int mt = 0; mt < 2; ++mt) {
            f16x8 a0 = lds8(&KV[(16 * mt + lc) * KST + 8 * lg]);
            f16x8 a1 = lds8(&KV[(16 * mt + lc) * KST + 8 * lg + 32]);
            #pragma unroll
            for (int qt = 0; qt < 4; ++qt) {
                f32x4 z = {0.f, 0.f, 0.f, 0.f};
                z = MFMA16(a0, qfa[qt], z);
                z = MFMA16(a1, qfb[qt], z);
                f32x4 p;
                #pragma unroll
                for (int rr = 0; rr < 4; ++rr)
                    p[rr] = __expf(z[rr]) * il[qt];
                f16x4 ph = { (_Float16)p[0], (_Float16)p[1],
                             (_Float16)p[2], (_Float16)p[3] };
                *(f16x4*)&Ps[(16 * qt + lc) * PST + 16 * mt + 4 * lg] = ph;
            }
        }
        __builtin_amdgcn_s_setprio(0);

        // ---- VT write (overwrites K region; wave-local DS is in-order)
        #pragma unroll
        for (int h = 0; h < 2; ++h)
            #pragma unroll
            for (int jj = 0; jj < 4; ++jj) {
                f16x4 col = { (_Float16)vr[0 + h][jj], (_Float16)vr[2 + h][jj],
                              (_Float16)vr[4 + h][jj], (_Float16)vr[6 + h][jj] };
                *(f16x4*)&KV[(8 * vdg + 4 * h + jj) * VST + 4 * vkq] = col;
            }
        // ---- K(t+1) loads issued BEFORE attn stores (vmcnt-order fix)
        {
            const int nk = ((t + 1 < NTB ? t + 1 : 0) * 4 + w) * WKT;
            #pragma unroll
            for (int i = 0; i < 8; ++i)
                kr[i] = *(const float4*)&Kp[(size_t)nk * ND + i * 256 + 4 * lane];
        }
        dsfence();               // Ps + VT visible to own reads

        // ---- PV
        f16x8 bf[4];
        #pragma unroll
        for (int qt = 0; qt < 4; ++qt)
            bf[qt] = lds8(&Ps[(16 * qt + lc) * PST + 8 * lg]);
        __builtin_amdgcn_s_setprio(1);
        #pragma unroll
        for (int dt = 0; dt < 4; ++dt) {
            f16x8 af = lds8(&KV[(16 * dt + lc) * VST + 8 * lg]);
            #pragma unroll
            for (int qt = 0; qt < 4; ++qt)
                acc[dt][qt] = MFMA16(af, bf[qt], acc[dt][qt]);
        }
        __builtin_amdgcn_s_setprio(0);

        // ---- attn stores: Ps readback, cvt, 1KB-contiguous (after K(t+1) issue)
        #pragma unroll
        for (int i = 0; i < 8; ++i) {
            const int qr = 8 * i + (lane >> 3);
            const int kc = 4 * (lane & 7);
            f16x4 ph = *(const f16x4*)&Ps[qr * PST + kc];
            f32x4 pf = { (float)ph[0], (float)ph[1], (float)ph[2], (float)ph[3] };
            *(f32x4*)&Ap[(size_t)qr * NS + kh * NKH + koff + kc] = pf;
        }
        __builtin_amdgcn_sched_barrier(0x7F);
    }

    // ---- merge partial O across waves, store ----
    __syncthreads();
    #pragma unroll
    for (int ww = 0; ww < 4; ++ww) {
        if (w == ww) {
            #pragma unroll
            for (int dt = 0; dt < 4; ++dt)
                #pragma unroll
                for (int qt = 0; qt < 4; ++qt) {
                    float* ad = &Obuf[(16 * qt + lc) * OST + 16 * dt + 4 * lg];
                    f32x4 v = acc[dt][qt];
                    if (ww > 0) v = v + *(const f32x4*)ad;
                    *(f32x4*)ad = v;
                }
        }
        __syncthreads();
    }
    #pragma unroll
    for (int dt = 0; dt < 4; ++dt) {
        f32x4 o = *(const f32x4*)&Obuf[(16 * w + lc) * OST + 16 * dt + 4 * lg];
        float* ad = &Op[(size_t)(16 * w + lc) * ND + 16 * dt + 4 * lg];
        if (accum) o = o + *(const f32x4*)ad;
        *(f32x4*)ad = o;
    }
}

// ========== kernel 3: O merge ==========
__global__ __launch_bounds__(256)
void add_o(float* __restrict__ O, const float* __restrict__ P)
{
    const size_t i = (size_t)blockIdx.x * 256 + threadIdx.x;
    f32x4* O4 = (f32x4*)O;
    const f32x4* P4 = (const f32x4*)P;
    O4[i] = O4[i] + P4[i];
}

extern "C" void kernel_launch(void* const* d_in, const int* in_sizes, int n_in,
                              void* d_out, int out_size, void* d_ws, size_t ws_size,
                              hipStream_t stream) {
    const float* q = (const float*)d_in[0];
    const float* k = (const float*)d_in[1];
    const float* v = (const float*)d_in[2];
    float* out  = (float*)d_out;
    float* attn = out + (size_t)NB * NH * NS * ND;   // outputs: (output, attn)
    float* wsO  = (float*)d_ws;
    const size_t oElems = (size_t)NB * NH * NS * ND; // 2M floats

    sdpa_stats<<<dim3(32 * NB * NH * 4), 256, 0, stream>>>(q, k, attn);

    if (ws_size >= oElems * sizeof(float)) {
        sdpa_passb<<<dim3(32 * NB * NH * 2), 256, 0, stream>>>(
            q, k, v, attn, out, wsO, 0, 1, 0);
        add_o<<<dim3(oElems / (256 * 4)), 256, 0, stream>>>(out, wsO);
    } else {
        sdpa_passb<<<dim3(32 * NB * NH), 256, 0, stream>>>(
            q, k, v, attn, out, out, 0, 0, 0);
        sdpa_passb<<<dim3(32 * NB * NH), 256, 0, stream>>>(
            q, k, v, attn, out, out, 1, 0, 1);
    }
}

// Round 18
// 91.069 us; speedup vs baseline: 2.0028x; 1.3805x over previous
//
#include <hip/hip_runtime.h>

#define NB 2
#define NH 8
#define NS 2048
#define ND 64
#define WKT 64              // keys per wave-tile (contiguous per-wave bands)
#define NTW 8               // tiles per wave per pass (512 keys / 64)
#define QST 68              // LDS strides (f16 elems)
#define KST 76
#define VST 68
#define PST 68
#define OST 68              // f32

typedef _Float16 f16x4 __attribute__((ext_vector_type(4)));
typedef _Float16 f16x8 __attribute__((ext_vector_type(8)));
typedef float    f32x4 __attribute__((ext_vector_type(4)));

#define MFMA16(A,B,C) __builtin_amdgcn_mfma_f32_16x16x32_f16((A),(B),(C),0,0,0)

static __device__ __forceinline__ f16x8 cat8(f16x4 a, f16x4 b) {
    return __builtin_shufflevector(a, b, 0, 1, 2, 3, 4, 5, 6, 7);
}
static __device__ __forceinline__ f16x4 tof16(float4 f) {
    return (f16x4){ (_Float16)f.x, (_Float16)f.y, (_Float16)f.z, (_Float16)f.w };
}
static __device__ __forceinline__ f16x8 lds8(const _Float16* p) {
    f16x4 a = *(const f16x4*)p;          // ds_read_b64 pair
    f16x4 b = *(const f16x4*)(p + 4);
    return cat8(a, b);
}
// wave-local staging fence: wait own LDS ops, pin DS reordering only
static __device__ __forceinline__ void dsfence() {
    asm volatile("s_waitcnt lgkmcnt(0)");
    __builtin_amdgcn_sched_barrier(0x7F);
}

__global__ __launch_bounds__(256, 2)
void sdpa_kernel(const float* __restrict__ Qg, const float* __restrict__ Kg,
                 const float* __restrict__ Vg, float* __restrict__ Og,
                 float* __restrict__ Ag)
{
    const int tid  = threadIdx.x;
    const int w    = tid >> 6;
    const int lane = tid & 63;
    const int lg   = lane >> 4;
    const int lc   = lane & 15;

    // XCD-pinned decode (proven: FETCH 103->12 MB): bid&7 = XCD, 2 heads/XCD.
    const int bid = blockIdx.x;
    const int xcd = bid & 7;
    const int j   = bid >> 3;           // 0..63
    const int bh  = 2 * xcd + (j >> 5); // 0..15
    const int qt_ = j & 31;             // 0..31

    const size_t base = (size_t)bh * NS * ND;
    const float* Qp = Qg + base + (size_t)qt_ * 64 * ND;
    const float* Kp = Kg + base;
    const float* Vp = Vg + base;
    float*       Op = Og + base + (size_t)qt_ * 64 * ND;
    float*       Ap = Ag + (size_t)bh * NS * NS + (size_t)qt_ * 64 * NS;

    // wave-private: KV[w] 9728 (K 64xKST76 / VT 64xVST68 TIME-SHARED) |
    // Ps[w] 8704. Qs (prologue), MLs (inter-pass), Obuf (epilogue) overlay.
    // Total 73728 B -> 2 blocks/CU (grid-pinned at 2 anyway).
    __shared__ __align__(16) unsigned char pool[73728];
    _Float16* Qs = (_Float16*)pool;                            // prologue only
    _Float16* KV = (_Float16*)(pool + (size_t)w * 9728);
    _Float16* Ps = (_Float16*)(pool + 38912 + (size_t)w * 8704);
    float*   MLs = (float*)(pool + 38912);                     // inter-pass
    float*  Obuf = (float*)pool;                               // epilogue

    // ---- stage Q (scaled by 1/T = 1/8, exact) cooperatively ----
    {
        const int srow = tid >> 4, sd0 = (tid & 15) * 4;
        #pragma unroll
        for (int it = 0; it < 4; ++it) {
            const int r = srow + 16 * it;
            float4 f = *(const float4*)&Qp[(size_t)r * ND + sd0];
            f16x4 h = { (_Float16)(f.x * 0.125f), (_Float16)(f.y * 0.125f),
                        (_Float16)(f.z * 0.125f), (_Float16)(f.w * 0.125f) };
            *(f16x4*)&Qs[r * QST + sd0] = h;
        }
    }
    __syncthreads();
    f16x8 qfa[4], qfb[4];        // every wave needs all 64 q columns
    #pragma unroll
    for (int qt = 0; qt < 4; ++qt) {
        qfa[qt] = lds8(&Qs[(16 * qt + lc) * QST + 8 * lg]);
        qfb[qt] = lds8(&Qs[(16 * qt + lc) * QST + 8 * lg + 32]);
    }
    __syncthreads();             // Qs dead; KV overlays it

    const int vkq = lane >> 3;   // V staging: key quad 4*vkq (within 32-half)
    const int vdg = lane & 7;    // V staging: d group 8*vdg

    // ---- K staging: 64 rows x 64 d, flat-coalesced 1KB/instr, 2 reg halves ----
    float4 kr0[8], kr1[8];
    auto loadK = [&](int koff) {
        #pragma unroll
        for (int i = 0; i < 8; ++i)
            kr0[i] = *(const float4*)&Kp[(size_t)koff * ND + i * 256 + 4 * lane];
        #pragma unroll
        for (int i = 0; i < 8; ++i)
            kr1[i] = *(const float4*)&Kp[(size_t)koff * ND + 2048 + i * 256 + 4 * lane];
    };
    auto writeK = [&]() {
        #pragma unroll
        for (int i = 0; i < 8; ++i)
            *(f16x4*)&KV[(4 * i + lg) * KST + 4 * lc] = tof16(kr0[i]);
        #pragma unroll
        for (int i = 0; i < 8; ++i)
            *(f16x4*)&KV[(32 + 4 * i + lg) * KST + 4 * lc] = tof16(kr1[i]);
    };

    float lacc[4] = {0.f, 0.f, 0.f, 0.f};

    // ============ PASS A: denominators (wave-private, contiguous bands) ============
    for (int t = 0; t < NTW; ++t) {
        const int koff = 512 * w + WKT * t;
        loadK(koff);
        writeK();
        dsfence();

        __builtin_amdgcn_s_setprio(1);
        #pragma unroll
        for (int mt = 0; mt < 4; ++mt) {
            f16x8 a0 = lds8(&KV[(16 * mt + lc) * KST + 8 * lg]);
            f16x8 a1 = lds8(&KV[(16 * mt + lc) * KST + 8 * lg + 32]);
            #pragma unroll
            for (int qt = 0; qt < 4; ++qt) {
                f32x4 z = {0.f, 0.f, 0.f, 0.f};
                z = MFMA16(a0, qfa[qt], z);
                z = MFMA16(a1, qfb[qt], z);
                #pragma unroll
                for (int r = 0; r < 4; ++r)
                    lacc[qt] += __expf(z[r]);
            }
        }
        __builtin_amdgcn_s_setprio(0);
        __builtin_amdgcn_sched_barrier(0x7F);   // reads stay before next writes
    }

    // ---- merge denominators across waves (max-free softmax) ----
    #pragma unroll
    for (int qt = 0; qt < 4; ++qt) {
        lacc[qt] += __shfl_xor(lacc[qt], 16);
        lacc[qt] += __shfl_xor(lacc[qt], 32);
    }
    __syncthreads();             // KV reads done everywhere; MLs region free
    if (lg == 0) {
        #pragma unroll
        for (int qt = 0; qt < 4; ++qt)
            MLs[w * 64 + 16 * qt + lc] = lacc[qt];
    }
    __syncthreads();
    float il[4];
    #pragma unroll
    for (int qt = 0; qt < 4; ++qt)
        il[qt] = 1.0f / (MLs[16 * qt + lc] + MLs[64 + 16 * qt + lc] +
                         MLs[128 + 16 * qt + lc] + MLs[192 + 16 * qt + lc]);
    __syncthreads();             // MLs dead; Ps overlays it

    // ============ PASS B: attn write + PV (K/VT time-share, wave-private) ============
    f32x4 acc[4][4];             // [dt][qt]
    #pragma unroll
    for (int dt = 0; dt < 4; ++dt)
        #pragma unroll
        for (int qt = 0; qt < 4; ++qt)
            acc[dt][qt] = {0.f, 0.f, 0.f, 0.f};

    for (int t = 0; t < NTW; ++t) {
        const int koff = 512 * w + WKT * t;
        loadK(koff);
        writeK();                // K into KV (kr regs die here)
        // ---- issue V loads for both 32-key halves (land during QK^T) ----
        float4 vr0[8], vr1[8];
        #pragma unroll
        for (int r = 0; r < 4; ++r)
            #pragma unroll
            for (int h = 0; h < 2; ++h) {
                vr0[2 * r + h] = *(const float4*)
                    &Vp[(size_t)(koff + 4 * vkq + r) * ND + 8 * vdg + 4 * h];
                vr1[2 * r + h] = *(const float4*)
                    &Vp[(size_t)(koff + 32 + 4 * vkq + r) * ND + 8 * vdg + 4 * h];
            }
        dsfence();               // K writes visible to own reads

        // ---- QK^T -> exp -> Ps (per-mt fused, low VGPR) ----
        __builtin_amdgcn_s_setprio(1);
        #pragma unroll
        for (int mt = 0; mt < 4; ++mt) {
            f16x8 a0 = lds8(&KV[(16 * mt + lc) * KST + 8 * lg]);
            f16x8 a1 = lds8(&KV[(16 * mt + lc) * KST + 8 * lg + 32]);
            #pragma unroll
            for (int qt = 0; qt < 4; ++qt) {
                f32x4 z = {0.f, 0.f, 0.f, 0.f};
                z = MFMA16(a0, qfa[qt], z);
                z = MFMA16(a1, qfb[qt], z);
                f32x4 p;
                #pragma unroll
                for (int r = 0; r < 4; ++r)
                    p[r] = __expf(z[r]) * il[qt];
                f16x4 ph = { (_Float16)p[0], (_Float16)p[1],
                             (_Float16)p[2], (_Float16)p[3] };
                *(f16x4*)&Ps[(16 * qt + lc) * PST + 16 * mt + 4 * lg] = ph;
            }
        }
        __builtin_amdgcn_s_setprio(0);

        // ---- VT writes into KV (after QK's last read; wave-local DS in-order) ----
        #pragma unroll
        for (int h = 0; h < 2; ++h)
            #pragma unroll
            for (int jj = 0; jj < 4; ++jj) {
                f16x4 c0 = { (_Float16)vr0[0 + h][jj], (_Float16)vr0[2 + h][jj],
                             (_Float16)vr0[4 + h][jj], (_Float16)vr0[6 + h][jj] };
                *(f16x4*)&KV[(8 * vdg + 4 * h + jj) * VST + 4 * vkq] = c0;
                f16x4 c1 = { (_Float16)vr1[0 + h][jj], (_Float16)vr1[2 + h][jj],
                             (_Float16)vr1[4 + h][jj], (_Float16)vr1[6 + h][jj] };
                *(f16x4*)&KV[(8 * vdg + 4 * h + jj) * VST + 32 + 4 * vkq] = c1;
            }
        dsfence();               // Ps + VT visible to own reads

        // ---- PV: O^T += V^T . P^T (two 32-key slices) ----
        f16x8 bfa[4], bfb[4];
        #pragma unroll
        for (int qt = 0; qt < 4; ++qt) {
            bfa[qt] = lds8(&Ps[(16 * qt + lc) * PST + 8 * lg]);
            bfb[qt] = lds8(&Ps[(16 * qt + lc) * PST + 32 + 8 * lg]);
        }
        __builtin_amdgcn_s_setprio(1);
        #pragma unroll
        for (int dt = 0; dt < 4; ++dt) {
            f16x8 af0 = lds8(&KV[(16 * dt + lc) * VST + 8 * lg]);
            f16x8 af1 = lds8(&KV[(16 * dt + lc) * VST + 32 + 8 * lg]);
            #pragma unroll
            for (int qt = 0; qt < 4; ++qt) {
                acc[dt][qt] = MFMA16(af0, bfa[qt], acc[dt][qt]);
                acc[dt][qt] = MFMA16(af1, bfb[qt], acc[dt][qt]);
            }
        }
        __builtin_amdgcn_s_setprio(0);

        // ---- attn store: Ps readback, cvt, 256B/row, sequential across tiles ----
        #pragma unroll
        for (int i = 0; i < 16; ++i) {
            const int qr = 4 * i + (lane >> 4);    // 0..63
            const int kc = 4 * (lane & 15);        // 0..60
            f16x4 ph = *(const f16x4*)&Ps[qr * PST + kc];
            f32x4 pf = { (float)ph[0], (float)ph[1], (float)ph[2], (float)ph[3] };
            *(f32x4*)&Ap[(size_t)qr * NS + koff + kc] = pf;
        }
        __builtin_amdgcn_sched_barrier(0x7F);   // reads precede next-tile writes
    }

    // ---- merge partial O across waves (sequential LDS accumulate), store ----
    __syncthreads();             // main-loop LDS dead; Obuf overlays
    #pragma unroll
    for (int ww = 0; ww < 4; ++ww) {
        if (w == ww) {
            #pragma unroll
            for (int dt = 0; dt < 4; ++dt)
                #pragma unroll
                for (int qt = 0; qt < 4; ++qt) {
                    float* ad = &Obuf[(16 * qt + lc) * OST + 16 * dt + 4 * lg];
                    f32x4 v = acc[dt][qt];
                    if (ww > 0) v = v + *(const f32x4*)ad;
                    *(f32x4*)ad = v;
                }
        }
        __syncthreads();
    }
    #pragma unroll
    for (int dt = 0; dt < 4; ++dt) {
        f32x4 o = *(const f32x4*)&Obuf[(16 * w + lc) * OST + 16 * dt + 4 * lg];
        *(f32x4*)&Op[(size_t)(16 * w + lc) * ND + 16 * dt + 4 * lg] = o;
    }
}

extern "C" void kernel_launch(void* const* d_in, const int* in_sizes, int n_in,
                              void* d_out, int out_size, void* d_ws, size_t ws_size,
                              hipStream_t stream) {
    const float* q = (const float*)d_in[0];
    const float* k = (const float*)d_in[1];
    const float* v = (const float*)d_in[2];
    float* out  = (float*)d_out;
    float* attn = out + (size_t)NB * NH * NS * ND;  // outputs: (output, attn)

    sdpa_kernel<<<dim3((NS / 64) * NB * NH), 256, 0, stream>>>(q, k, v, out, attn);
}